// Round 1
// baseline (588.227 us; speedup 1.0000x reference)
//
#include <hip/hip_runtime.h>
#include <hip/hip_bf16.h>

typedef __bf16 bf16;
typedef __attribute__((ext_vector_type(8))) bf16 bf16x8;
typedef __attribute__((ext_vector_type(4))) bf16 bf16x4;
typedef __attribute__((ext_vector_type(4))) float f32x4;

#define SEQ    4096
#define DIM    256
#define NBATCH 4
#define NROWS  (NBATCH*SEQ)      // 16384
#define NEGV   (-6.25e7f)        // -1e9 / sqrt(256)

__device__ __forceinline__ int imax(int a, int b) { return a > b ? a : b; }
__device__ __forceinline__ int imin(int a, int b) { return a < b ? a : b; }

// ================= weights f32 -> bf16 =================
__global__ __launch_bounds__(256) void cvt_w_kernel(
    const float* __restrict__ w0, const float* __restrict__ w1,
    const float* __restrict__ w2, const float* __restrict__ w3,
    bf16* __restrict__ o0, bf16* __restrict__ o1,
    bf16* __restrict__ o2, bf16* __restrict__ o3)
{
    const float* s; bf16* d;
    switch (blockIdx.y) {
        case 0:  s = w0; d = o0; break;
        case 1:  s = w1; d = o1; break;
        case 2:  s = w2; d = o2; break;
        default: s = w3; d = o3; break;
    }
    int i = (blockIdx.x*256 + threadIdx.x)*4;
    f32x4 v = *(const f32x4*)(s + i);
    bf16x4 b;
#pragma unroll
    for (int j = 0; j < 4; ++j) b[j] = (bf16)v[j];
    *(bf16x4*)(d + i) = b;
}

// ================= projection GEMM: out = X @ W^T + bias =================
// X: [16384,256] (f32 or bf16). W: bf16 [256 out][256 in]. bias f32[256].
// OUT_MODE: 0 = bf16 row-major, 1 = bf16 transposed per batch [4][256][4096], 2 = f32 row-major
template<int OUT_MODE, bool IN_BF16, bool DO_SCALE>
__global__ __launch_bounds__(256, 2) void proj_kernel(
    const void* __restrict__ Xv, const bf16* __restrict__ W,
    const float* __restrict__ bias, void* __restrict__ outv)
{
    __shared__ bf16 X_lds[64*256];   // 32 KB, XOR-swizzled
    const int tid = threadIdx.x;
    const int tok0 = blockIdx.x * 64;

    if (IN_BF16) {
        const bf16* X = (const bf16*)Xv;
#pragma unroll
        for (int i = 0; i < 8; ++i) {
            int g = i*256 + tid;
            int tok = g >> 5, c8 = (g & 31)*8;
            bf16x8 v = *(const bf16x8*)(X + (size_t)(tok0+tok)*DIM + c8);
            *(bf16x8*)(X_lds + tok*256 + (c8 ^ ((tok & 7) << 3))) = v;
        }
    } else {
        const float* X = (const float*)Xv;
#pragma unroll
        for (int i = 0; i < 8; ++i) {
            int g = i*256 + tid;
            int tok = g >> 5, c8 = (g & 31)*8;
            const f32x4* p = (const f32x4*)(X + (size_t)(tok0+tok)*DIM + c8);
            f32x4 a = p[0], b2 = p[1];
            bf16x8 v;
#pragma unroll
            for (int j = 0; j < 4; ++j) { v[j] = (bf16)a[j]; v[4+j] = (bf16)b2[j]; }
            *(bf16x8*)(X_lds + tok*256 + (c8 ^ ((tok & 7) << 3))) = v;
        }
    }
    __syncthreads();

    const int wave = tid >> 6, lane = tid & 63;
    const int l16 = lane & 15, lhi = lane >> 4;
    const int oc0 = wave * 64;

    f32x4 acc[4][4];
#pragma unroll
    for (int m = 0; m < 4; ++m)
#pragma unroll
        for (int n = 0; n < 4; ++n) acc[m][n] = (f32x4){0.f,0.f,0.f,0.f};

#pragma unroll
    for (int kk = 0; kk < 8; ++kk) {
        const int koff = kk*32 + 8*lhi;
        bf16x8 af[4], bf_[4];
#pragma unroll
        for (int m = 0; m < 4; ++m) {
            int row = m*16 + l16;
            af[m] = *(const bf16x8*)(X_lds + row*256 + (koff ^ ((row & 7) << 3)));
        }
#pragma unroll
        for (int n = 0; n < 4; ++n) {
            int o = oc0 + n*16 + l16;
            bf_[n] = *(const bf16x8*)(W + (size_t)o*DIM + koff);
        }
#pragma unroll
        for (int m = 0; m < 4; ++m)
#pragma unroll
            for (int n = 0; n < 4; ++n)
                acc[m][n] = __builtin_amdgcn_mfma_f32_16x16x32_bf16(af[m], bf_[n], acc[m][n], 0, 0, 0);
    }

#pragma unroll
    for (int n = 0; n < 4; ++n) {
        const int o = oc0 + n*16 + l16;
        const float bb = bias[o];
#pragma unroll
        for (int m = 0; m < 4; ++m) {
            const int tk0 = tok0 + m*16 + lhi*4;
            if (OUT_MODE == 1) {
                bf16x4 pk;
#pragma unroll
                for (int r = 0; r < 4; ++r) pk[r] = (bf16)(acc[m][n][r] + bb);
                const int bi = tk0 >> 12, tk = tk0 & (SEQ-1);
                *(bf16x4*)((bf16*)outv + (size_t)bi*DIM*SEQ + (size_t)o*SEQ + tk) = pk;
            } else {
#pragma unroll
                for (int r = 0; r < 4; ++r) {
                    float v = acc[m][n][r] + bb;
                    if (DO_SCALE) v *= 0.0625f;
                    if (OUT_MODE == 0) ((bf16*)outv)[(size_t)(tk0+r)*DIM + o] = (bf16)v;
                    else               ((float*)outv)[(size_t)(tk0+r)*DIM + o] = v;
                }
            }
        }
    }
}

// ================= flash attention, K-split=2, partial (m,l,O) out =================
// grid (NBATCH, 64, 2), block 128 (2 waves x 32 q-rows each). KV tile = 64 keys.
__global__ __launch_bounds__(128, 1) void attn_kernel(
    const bf16* __restrict__ Qp, const bf16* __restrict__ Kp,
    const bf16* __restrict__ Vt, const int* __restrict__ mask,
    float* __restrict__ pm, float* __restrict__ pl, float* __restrict__ pO)
{
    __shared__ __align__(16) char smem[65536];
    bf16* K_lds = (bf16*)smem;            // [64][256] swizzled; first 8KB doubles as P after barrier
    bf16* V_lds = (bf16*)(smem + 32768);  // [256][64] swizzled

    const int tid  = threadIdx.x;
    const int wave = tid >> 6, lane = tid & 63;
    const int l16  = lane & 15, lhi = lane >> 4;
    const int b    = blockIdx.x;
    const int qt   = blockIdx.y;
    const int ks   = blockIdx.z;
    const int kb0  = ks * 2048;
    const int q0   = qt*64 + wave*32;
    const size_t bQ = (size_t)b * SEQ * DIM;

    // per-lane row lengths for the 8 output rows this lane produces
    int L_[2][4];
#pragma unroll
    for (int mt = 0; mt < 2; ++mt)
#pragma unroll
        for (int r = 0; r < 4; ++r)
            L_[mt][r] = mask[b*SEQ + q0 + mt*16 + lhi*4 + r];
    int Lw = 0;
#pragma unroll
    for (int mt = 0; mt < 2; ++mt)
#pragma unroll
        for (int r = 0; r < 4; ++r) Lw = imax(Lw, L_[mt][r]);
#pragma unroll
    for (int d = 1; d < 64; d <<= 1) Lw = imax(Lw, __shfl_xor(Lw, d));

    // block-max length -> dynamic tile count (prefix masks => can bound the loop)
    {
        int* sI = (int*)smem;
        if (lane == 0) sI[wave] = Lw;
    }
    __syncthreads();
    const int Lb = imax(((int*)smem)[0], ((int*)smem)[1]);
    __syncthreads();
    const int ktEnd = imin(32, imax(0, Lb - kb0 + 63) >> 6);

    // Q fragments in registers: 2 M-tiles x 8 k-steps (Q pre-scaled by 1/16)
    bf16x8 qf[2][8];
#pragma unroll
    for (int mt = 0; mt < 2; ++mt) {
        const bf16* qrow = Qp + bQ + (size_t)(q0 + mt*16 + l16)*DIM + 8*lhi;
#pragma unroll
        for (int kk = 0; kk < 8; ++kk) qf[mt][kk] = *(const bf16x8*)(qrow + kk*32);
    }

    float m_run[2][4], l_run[2][4];
#pragma unroll
    for (int mt = 0; mt < 2; ++mt)
#pragma unroll
        for (int r = 0; r < 4; ++r) { m_run[mt][r] = NEGV; l_run[mt][r] = 0.f; }
    f32x4 oacc[2][16];
#pragma unroll
    for (int mt = 0; mt < 2; ++mt)
#pragma unroll
        for (int t = 0; t < 16; ++t) oacc[mt][t] = (f32x4){0.f,0.f,0.f,0.f};

    const bf16* Ksrc0 = Kp + bQ;
    const bf16* Vsrc0 = Vt + (size_t)b * DIM * SEQ;

    for (int kt = 0; kt < ktEnd; ++kt) {
        const int kb = kb0 + kt*64;
        // ---- stage K [64][256] and V^T [256][64] (reg-staged, XOR swizzle) ----
        {
            const bf16* Ksrc = Ksrc0 + (size_t)kb*DIM;
#pragma unroll
            for (int i = 0; i < 16; ++i) {
                int g = i*128 + tid;
                int key = g >> 5, c8 = (g & 31)*8;
                bf16x8 v = *(const bf16x8*)(Ksrc + key*DIM + c8);
                *(bf16x8*)(K_lds + key*256 + (c8 ^ ((key & 7) << 3))) = v;
            }
            const bf16* Vsrc = Vsrc0 + kb;
#pragma unroll
            for (int i = 0; i < 16; ++i) {
                int g = i*128 + tid;
                int dd = g >> 3, k8 = (g & 7)*8;
                bf16x8 v = *(const bf16x8*)(Vsrc + (size_t)dd*SEQ + k8);
                *(bf16x8*)(V_lds + dd*64 + (k8 ^ ((dd & 7) << 3))) = v;
            }
        }
        __syncthreads();

        const bool active = (kb < Lw);   // wave-uniform
        float p[2][4][4];
        float scale[2][4];
        if (active) {
            // ---- QK^T ----
            f32x4 s[2][4];
#pragma unroll
            for (int mt = 0; mt < 2; ++mt)
#pragma unroll
                for (int n = 0; n < 4; ++n) s[mt][n] = (f32x4){0.f,0.f,0.f,0.f};
#pragma unroll
            for (int kk = 0; kk < 8; ++kk) {
                const int koff = kk*32 + 8*lhi;
                bf16x8 bfr[4];
#pragma unroll
                for (int n = 0; n < 4; ++n) {
                    int key = n*16 + l16;
                    bfr[n] = *(const bf16x8*)(K_lds + key*256 + (koff ^ ((key & 7) << 3)));
                }
#pragma unroll
                for (int mt = 0; mt < 2; ++mt)
#pragma unroll
                    for (int n = 0; n < 4; ++n)
                        s[mt][n] = __builtin_amdgcn_mfma_f32_16x16x32_bf16(qf[mt][kk], bfr[n], s[mt][n], 0, 0, 0);
            }
            // ---- mask + online softmax (C layout: row=lhi*4+r, col=key=n*16+l16) ----
            float tmax[2][4];
#pragma unroll
            for (int mt = 0; mt < 2; ++mt)
#pragma unroll
                for (int r = 0; r < 4; ++r) tmax[mt][r] = NEGV;
#pragma unroll
            for (int n = 0; n < 4; ++n) {
                const int key = kb + n*16 + l16;
#pragma unroll
                for (int mt = 0; mt < 2; ++mt)
#pragma unroll
                    for (int r = 0; r < 4; ++r) {
                        float v = (key < L_[mt][r]) ? s[mt][n][r] : NEGV;
                        p[mt][n][r] = v;
                        tmax[mt][r] = fmaxf(tmax[mt][r], v);
                    }
            }
#pragma unroll
            for (int w = 1; w < 16; w <<= 1)
#pragma unroll
                for (int mt = 0; mt < 2; ++mt)
#pragma unroll
                    for (int r = 0; r < 4; ++r)
                        tmax[mt][r] = fmaxf(tmax[mt][r], __shfl_xor(tmax[mt][r], w));
            float rsum[2][4];
#pragma unroll
            for (int mt = 0; mt < 2; ++mt)
#pragma unroll
                for (int r = 0; r < 4; ++r) {
                    float M = fmaxf(m_run[mt][r], tmax[mt][r]);
                    scale[mt][r] = __expf(m_run[mt][r] - M);
                    m_run[mt][r] = M;
                    rsum[mt][r] = 0.f;
                }
#pragma unroll
            for (int n = 0; n < 4; ++n)
#pragma unroll
                for (int mt = 0; mt < 2; ++mt)
#pragma unroll
                    for (int r = 0; r < 4; ++r) {
                        float e = __expf(p[mt][n][r] - m_run[mt][r]);
                        p[mt][n][r] = e;
                        rsum[mt][r] += e;
                    }
#pragma unroll
            for (int w = 1; w < 16; w <<= 1)
#pragma unroll
                for (int mt = 0; mt < 2; ++mt)
#pragma unroll
                    for (int r = 0; r < 4; ++r)
                        rsum[mt][r] += __shfl_xor(rsum[mt][r], w);
#pragma unroll
            for (int mt = 0; mt < 2; ++mt)
#pragma unroll
                for (int r = 0; r < 4; ++r)
                    l_run[mt][r] = l_run[mt][r]*scale[mt][r] + rsum[mt][r];
#pragma unroll
            for (int mt = 0; mt < 2; ++mt)
#pragma unroll
                for (int t = 0; t < 16; ++t)
#pragma unroll
                    for (int r = 0; r < 4; ++r)
                        oacc[mt][t][r] *= scale[mt][r];
        }
        __syncthreads();   // all waves done reading K_lds -> its head may hold P now
        if (active) {
            // ---- P: C-layout -> A-fragment layout via per-wave LDS transpose ----
            bf16* Pw = (bf16*)smem + wave*2048;   // 32x64 bf16 = 4KB per wave
#pragma unroll
            for (int mt = 0; mt < 2; ++mt)
#pragma unroll
                for (int n = 0; n < 4; ++n) {
                    const int col = n*16 + l16;
#pragma unroll
                    for (int r = 0; r < 4; ++r) {
                        const int row = mt*16 + lhi*4 + r;
                        Pw[row*64 + (col ^ ((row & 7) << 3))] = (bf16)p[mt][n][r];
                    }
                }
            asm volatile("s_waitcnt lgkmcnt(0)" ::: "memory");
            bf16x8 pa[2][2];
#pragma unroll
            for (int mt = 0; mt < 2; ++mt)
#pragma unroll
                for (int ksb = 0; ksb < 2; ++ksb) {
                    const int row = mt*16 + l16;
                    const int off = ksb*32 + 8*lhi;
                    pa[mt][ksb] = *(const bf16x8*)(Pw + row*64 + (off ^ ((row & 7) << 3)));
                }
            // ---- PV ----
#pragma unroll
            for (int t = 0; t < 16; ++t) {
                const int d = t*16 + l16;
#pragma unroll
                for (int ksb = 0; ksb < 2; ++ksb) {
                    const int off = ksb*32 + 8*lhi;
                    bf16x8 vf = *(const bf16x8*)(V_lds + d*64 + (off ^ ((d & 7) << 3)));
#pragma unroll
                    for (int mt = 0; mt < 2; ++mt)
                        oacc[mt][t] = __builtin_amdgcn_mfma_f32_16x16x32_bf16(pa[mt][ksb], vf, oacc[mt][t], 0, 0, 0);
                }
            }
        }
        __syncthreads();   // P/V reads complete before next stage overwrites
    }

    // ---- write partials (merge kernel divides) ----
    const int ksOff = ks * NROWS;
#pragma unroll
    for (int mt = 0; mt < 2; ++mt)
#pragma unroll
        for (int r = 0; r < 4; ++r) {
            const int row = b*SEQ + q0 + mt*16 + lhi*4 + r;
            if (l16 == 0) { pm[ksOff + row] = m_run[mt][r]; pl[ksOff + row] = l_run[mt][r]; }
            float* dst = pO + (size_t)(ksOff + row)*DIM + l16;
#pragma unroll
            for (int t = 0; t < 16; ++t) dst[t*16] = oacc[mt][t][r];
        }
}

// ================= merge two K-split partials -> att bf16 =================
__global__ __launch_bounds__(256) void merge_kernel(
    const float* __restrict__ pO, const float* __restrict__ pm,
    const float* __restrict__ pl, bf16* __restrict__ att)
{
    const int t = blockIdx.x*256 + threadIdx.x;
    const int row = t >> 5;
    const int d0 = (t & 31)*8;
    float m0 = pm[row],        m1 = pm[NROWS + row];
    float l0 = pl[row],        l1 = pl[NROWS + row];
    float M  = fmaxf(m0, m1);
    float e0 = __expf(m0 - M), e1 = __expf(m1 - M);
    float inv = 1.f / (l0*e0 + l1*e1);
    e0 *= inv; e1 *= inv;
    const float* p0 = pO + (size_t)row*DIM + d0;
    const float* p1 = pO + (size_t)NROWS*DIM + (size_t)row*DIM + d0;
    bf16x8 o;
#pragma unroll
    for (int j = 0; j < 8; ++j) o[j] = (bf16)(p0[j]*e0 + p1[j]*e1);
    *(bf16x8*)(att + (size_t)row*DIM + d0) = o;
}

// ================= launcher =================
extern "C" void kernel_launch(void* const* d_in, const int* in_sizes, int n_in,
                              void* d_out, int out_size, void* d_ws, size_t ws_size,
                              hipStream_t stream)
{
    (void)in_sizes; (void)n_in; (void)out_size; (void)ws_size;
    const float* queries = (const float*)d_in[0];
    const float* keys    = (const float*)d_in[1];
    const float* values  = (const float*)d_in[2];
    const int*   mask    = (const int*)  d_in[3];
    const float* Wq = (const float*)d_in[4];  const float* bq = (const float*)d_in[5];
    const float* Wk = (const float*)d_in[6];  const float* bk = (const float*)d_in[7];
    const float* Wv = (const float*)d_in[8];  const float* bv = (const float*)d_in[9];
    const float* Wo = (const float*)d_in[10]; const float* bo = (const float*)d_in[11];

    char* ws = (char*)d_ws;
    bf16* WqB = (bf16*)(ws);
    bf16* WkB = (bf16*)(ws + (size_t)(1<<17));
    bf16* WvB = (bf16*)(ws + (size_t)2*(1<<17));
    bf16* WoB = (bf16*)(ws + (size_t)3*(1<<17));
    bf16* Qp  = (bf16*)(ws + (size_t)(1<<20));
    bf16* Kp  = (bf16*)(ws + (size_t)(1<<20) + (size_t)(1<<23));
    bf16* Vt  = (bf16*)(ws + (size_t)(1<<20) + (size_t)2*(1<<23));
    bf16* att = (bf16*)(ws + (size_t)(1<<20) + (size_t)3*(1<<23));
    float* pm = (float*)(ws + (size_t)(1<<20) + (size_t)4*(1<<23));
    float* pl = pm + 2*NROWS;
    float* pO = (float*)(ws + (size_t)(1<<20) + (size_t)4*(1<<23) + (size_t)(1<<18));

    cvt_w_kernel<<<dim3(64,4), 256, 0, stream>>>(Wq, Wk, Wv, Wo, WqB, WkB, WvB, WoB);
    proj_kernel<0,false,true ><<<dim3(256), 256, 0, stream>>>(queries, WqB, bq, Qp);
    proj_kernel<0,false,false><<<dim3(256), 256, 0, stream>>>(keys,    WkB, bk, Kp);
    proj_kernel<1,false,false><<<dim3(256), 256, 0, stream>>>(values,  WvB, bv, Vt);
    attn_kernel<<<dim3(NBATCH,64,2), 128, 0, stream>>>(Qp, Kp, Vt, mask, pm, pl, pO);
    merge_kernel<<<dim3(NROWS/8), 256, 0, stream>>>(pO, pm, pl, att);
    proj_kernel<2,true,false><<<dim3(256), 256, 0, stream>>>(att, WoB, bo, d_out);
}

// Round 3
// 358.723 us; speedup vs baseline: 1.6398x; 1.6398x over previous
//
#include <hip/hip_runtime.h>
#include <hip/hip_bf16.h>

typedef __bf16 bf16;
typedef __attribute__((ext_vector_type(8))) bf16 bf16x8;
typedef __attribute__((ext_vector_type(4))) bf16 bf16x4;
typedef __attribute__((ext_vector_type(4))) float f32x4;

#define SEQ    4096
#define DIM    256
#define NBATCH 4
#define NROWS  (NBATCH*SEQ)      // 16384
#define NEGV   (-6.25e7f)        // -1e9 / sqrt(256)

__device__ __forceinline__ int imax(int a, int b) { return a > b ? a : b; }
__device__ __forceinline__ int imin(int a, int b) { return a < b ? a : b; }

// ================= weights f32 -> bf16 =================
__global__ __launch_bounds__(256) void cvt_w_kernel(
    const float* __restrict__ w0, const float* __restrict__ w1,
    const float* __restrict__ w2, const float* __restrict__ w3,
    bf16* __restrict__ o0, bf16* __restrict__ o1,
    bf16* __restrict__ o2, bf16* __restrict__ o3)
{
    const float* s; bf16* d;
    switch (blockIdx.y) {
        case 0:  s = w0; d = o0; break;
        case 1:  s = w1; d = o1; break;
        case 2:  s = w2; d = o2; break;
        default: s = w3; d = o3; break;
    }
    int i = (blockIdx.x*256 + threadIdx.x)*4;
    f32x4 v = *(const f32x4*)(s + i);
    bf16x4 b;
#pragma unroll
    for (int j = 0; j < 4; ++j) b[j] = (bf16)v[j];
    *(bf16x4*)(d + i) = b;
}

// ================= projection GEMM: out = X @ W^T + bias =================
// Token tile = 32 -> 512 blocks (2+/CU). 4 waves, each 64 output cols.
// OUT_MODE: 0 = bf16 row-major, 1 = bf16 transposed per batch [4][256][4096], 2 = f32 row-major
template<int OUT_MODE, bool IN_BF16, bool DO_SCALE>
__global__ __launch_bounds__(256, 4) void proj_kernel(
    const void* __restrict__ Xv, const bf16* __restrict__ W,
    const float* __restrict__ bias, void* __restrict__ outv)
{
    __shared__ bf16 X_lds[32*256];   // 16 KB, XOR-swizzled
    const int tid = threadIdx.x;
    const int tok0 = blockIdx.x * 32;

    if (IN_BF16) {
        const bf16* X = (const bf16*)Xv;
#pragma unroll
        for (int i = 0; i < 4; ++i) {
            int g = i*256 + tid;
            int tok = g >> 5, c8 = (g & 31)*8;
            bf16x8 v = *(const bf16x8*)(X + (size_t)(tok0+tok)*DIM + c8);
            *(bf16x8*)(X_lds + tok*256 + (c8 ^ ((tok & 7) << 3))) = v;
        }
    } else {
        const float* X = (const float*)Xv;
#pragma unroll
        for (int i = 0; i < 4; ++i) {
            int g = i*256 + tid;
            int tok = g >> 5, c8 = (g & 31)*8;
            const f32x4* p = (const f32x4*)(X + (size_t)(tok0+tok)*DIM + c8);
            f32x4 a = p[0], b2 = p[1];
            bf16x8 v;
#pragma unroll
            for (int j = 0; j < 4; ++j) { v[j] = (bf16)a[j]; v[4+j] = (bf16)b2[j]; }
            *(bf16x8*)(X_lds + tok*256 + (c8 ^ ((tok & 7) << 3))) = v;
        }
    }
    __syncthreads();

    const int wave = tid >> 6, lane = tid & 63;
    const int l16 = lane & 15, lhi = lane >> 4;
    const int oc0 = wave * 64;

    f32x4 acc[2][4];
#pragma unroll
    for (int m = 0; m < 2; ++m)
#pragma unroll
        for (int n = 0; n < 4; ++n) acc[m][n] = (f32x4){0.f,0.f,0.f,0.f};

#pragma unroll
    for (int kk = 0; kk < 8; ++kk) {
        const int koff = kk*32 + 8*lhi;
        bf16x8 af[2], bf_[4];
#pragma unroll
        for (int m = 0; m < 2; ++m) {
            int row = m*16 + l16;
            af[m] = *(const bf16x8*)(X_lds + row*256 + (koff ^ ((row & 7) << 3)));
        }
#pragma unroll
        for (int n = 0; n < 4; ++n) {
            int o = oc0 + n*16 + l16;
            bf_[n] = *(const bf16x8*)(W + (size_t)o*DIM + koff);
        }
#pragma unroll
        for (int m = 0; m < 2; ++m)
#pragma unroll
            for (int n = 0; n < 4; ++n)
                acc[m][n] = __builtin_amdgcn_mfma_f32_16x16x32_bf16(af[m], bf_[n], acc[m][n], 0, 0, 0);
    }

#pragma unroll
    for (int n = 0; n < 4; ++n) {
        const int o = oc0 + n*16 + l16;
        const float bb = bias[o];
#pragma unroll
        for (int m = 0; m < 2; ++m) {
            const int tk0 = tok0 + m*16 + lhi*4;
            if (OUT_MODE == 1) {
                bf16x4 pk;
#pragma unroll
                for (int r = 0; r < 4; ++r) pk[r] = (bf16)(acc[m][n][r] + bb);
                const int bi = tk0 >> 12, tk = tk0 & (SEQ-1);
                *(bf16x4*)((bf16*)outv + (size_t)bi*DIM*SEQ + (size_t)o*SEQ + tk) = pk;
            } else {
#pragma unroll
                for (int r = 0; r < 4; ++r) {
                    float v = acc[m][n][r] + bb;
                    if (DO_SCALE) v *= 0.0625f;
                    if (OUT_MODE == 0) ((bf16*)outv)[(size_t)(tk0+r)*DIM + o] = (bf16)v;
                    else               ((float*)outv)[(size_t)(tk0+r)*DIM + o] = v;
                }
            }
        }
    }
}

// ================= staging helpers (reg-staged, async split) =================
__device__ __forceinline__ void stage_issue(
    const bf16* __restrict__ Ksrc, const bf16* __restrict__ Vsrc,
    int tid, bf16x8 (&kr)[8], bf16x8 (&vr)[8])
{
#pragma unroll
    for (int i = 0; i < 8; ++i) {
        int g = i*256 + tid;
        kr[i] = *(const bf16x8*)(Ksrc + (size_t)(g >> 5)*DIM + (g & 31)*8);
    }
#pragma unroll
    for (int i = 0; i < 8; ++i) {
        int g = i*256 + tid;
        vr[i] = *(const bf16x8*)(Vsrc + (size_t)(g >> 3)*SEQ + (g & 7)*8);
    }
}

__device__ __forceinline__ void stage_write(
    bf16* __restrict__ K_lds, bf16* __restrict__ V_lds,
    int tid, const bf16x8 (&kr)[8], const bf16x8 (&vr)[8])
{
#pragma unroll
    for (int i = 0; i < 8; ++i) {
        int g = i*256 + tid;
        int key = g >> 5, c8 = (g & 31)*8;
        *(bf16x8*)(K_lds + key*256 + (c8 ^ ((key & 7) << 3))) = kr[i];
    }
#pragma unroll
    for (int i = 0; i < 8; ++i) {
        int g = i*256 + tid;
        int dd = g >> 3, k8 = (g & 7)*8;
        *(bf16x8*)(V_lds + dd*64 + (k8 ^ ((dd & 7) << 3))) = vr[i];
    }
}

// ================= flash attention, K-split=2, partial (m,l,O) out =================
// grid (NBATCH, 64, 2), block 256 (4 waves x 16 q-rows). KV tile = 64 keys.
__global__ __launch_bounds__(256, 2) void attn_kernel(
    const bf16* __restrict__ Qp, const bf16* __restrict__ Kp,
    const bf16* __restrict__ Vt, const int* __restrict__ mask,
    float* __restrict__ pm, float* __restrict__ pl, float* __restrict__ pO)
{
    __shared__ __align__(16) char smem[65536];
    bf16* K_lds = (bf16*)smem;            // [64][256] swizzled; head doubles as P after barrier
    bf16* V_lds = (bf16*)(smem + 32768);  // [256][64] swizzled

    const int tid  = threadIdx.x;
    const int wave = tid >> 6, lane = tid & 63;
    const int l16  = lane & 15, lhi = lane >> 4;
    const int b    = blockIdx.x;
    const int qt   = blockIdx.y;
    const int ks   = blockIdx.z;
    const int kb0  = ks * 2048;
    const int q0w  = qt*64 + wave*16;
    const size_t bQ = (size_t)b * SEQ * DIM;

    // ---- lengths via pure shuffles: lane holds mask of block-row `lane` ----
    const int mv = mask[b*SEQ + qt*64 + lane];
    int t16 = mv;
#pragma unroll
    for (int w = 1; w < 16; w <<= 1) t16 = imax(t16, __shfl_xor(t16, w));
    const int Lw = __shfl(t16, wave*16);           // this wave's 16-row max
    int Lb = t16;
#pragma unroll
    for (int w = 16; w < 64; w <<= 1) Lb = imax(Lb, __shfl_xor(Lb, w));
    int L_[4];
#pragma unroll
    for (int r = 0; r < 4; ++r) L_[r] = __shfl(mv, wave*16 + 4*lhi + r);

    const int ktEnd = imin(32, (imax(0, Lb - kb0) + 63) >> 6);

    // ---- Q fragments in registers (Q pre-scaled by 1/16) ----
    bf16x8 qf[8];
    {
        const bf16* qrow = Qp + bQ + (size_t)(q0w + l16)*DIM + 8*lhi;
#pragma unroll
        for (int kk = 0; kk < 8; ++kk) qf[kk] = *(const bf16x8*)(qrow + kk*32);
    }

    float m_run[4], l_run[4];
#pragma unroll
    for (int r = 0; r < 4; ++r) { m_run[r] = NEGV; l_run[r] = 0.f; }
    f32x4 oacc[16];
#pragma unroll
    for (int t = 0; t < 16; ++t) oacc[t] = (f32x4){0.f,0.f,0.f,0.f};

    const bf16* Ksrc0 = Kp + bQ;
    const bf16* Vsrc0 = Vt + (size_t)b * DIM * SEQ;

    bf16x8 kr[8], vr[8];
    if (ktEnd > 0) {
        stage_issue(Ksrc0 + (size_t)kb0*DIM, Vsrc0 + kb0, tid, kr, vr);
        stage_write(K_lds, V_lds, tid, kr, vr);
    }
    __syncthreads();

    for (int kt = 0; kt < ktEnd; ++kt) {
        const int kb = kb0 + kt*64;
        const bool more = (kt + 1 < ktEnd);
        if (more)  // issue next tile's loads early; they drain under compute (T14)
            stage_issue(Ksrc0 + (size_t)(kb + 64)*DIM, Vsrc0 + kb + 64, tid, kr, vr);

        const bool active = (kb < Lw);   // wave-uniform
        float p[4][4];
        if (active) {
            // ---- QK^T ----
            f32x4 s[4];
#pragma unroll
            for (int n = 0; n < 4; ++n) s[n] = (f32x4){0.f,0.f,0.f,0.f};
            __builtin_amdgcn_s_setprio(1);
#pragma unroll
            for (int kk = 0; kk < 8; ++kk) {
                const int koff = kk*32 + 8*lhi;
                bf16x8 bfr[4];
#pragma unroll
                for (int n = 0; n < 4; ++n) {
                    int key = n*16 + l16;
                    bfr[n] = *(const bf16x8*)(K_lds + key*256 + (koff ^ ((key & 7) << 3)));
                }
#pragma unroll
                for (int n = 0; n < 4; ++n)
                    s[n] = __builtin_amdgcn_mfma_f32_16x16x32_bf16(qf[kk], bfr[n], s[n], 0, 0, 0);
            }
            __builtin_amdgcn_s_setprio(0);

            // ---- mask + online softmax (C layout: row=4*lhi+r, col=key=n*16+l16) ----
            float tmax[4];
#pragma unroll
            for (int r = 0; r < 4; ++r) tmax[r] = NEGV;
#pragma unroll
            for (int n = 0; n < 4; ++n) {
                const int key = kb + n*16 + l16;
#pragma unroll
                for (int r = 0; r < 4; ++r) {
                    float v = (key < L_[r]) ? s[n][r] : NEGV;
                    p[n][r] = v;
                    tmax[r] = fmaxf(tmax[r], v);
                }
            }
#pragma unroll
            for (int w = 1; w < 16; w <<= 1)
#pragma unroll
                for (int r = 0; r < 4; ++r)
                    tmax[r] = fmaxf(tmax[r], __shfl_xor(tmax[r], w));

            // T13 defer-rescale: only pay the O-rescale when max really grew
            bool need = false;
#pragma unroll
            for (int r = 0; r < 4; ++r) need |= (tmax[r] > m_run[r] + 8.f);
            if (__any(need)) {
                float sc[4];
#pragma unroll
                for (int r = 0; r < 4; ++r) {
                    float M = fmaxf(m_run[r], tmax[r]);
                    sc[r] = __expf(m_run[r] - M);
                    m_run[r] = M;
                    l_run[r] *= sc[r];
                }
#pragma unroll
                for (int t = 0; t < 16; ++t)
#pragma unroll
                    for (int r = 0; r < 4; ++r) oacc[t][r] *= sc[r];
            }
            float rsum[4];
#pragma unroll
            for (int r = 0; r < 4; ++r) rsum[r] = 0.f;
#pragma unroll
            for (int n = 0; n < 4; ++n)
#pragma unroll
                for (int r = 0; r < 4; ++r) {
                    float e = __expf(p[n][r] - m_run[r]);
                    p[n][r] = e;
                    rsum[r] += e;
                }
#pragma unroll
            for (int w = 1; w < 16; w <<= 1)
#pragma unroll
                for (int r = 0; r < 4; ++r)
                    rsum[r] += __shfl_xor(rsum[r], w);
#pragma unroll
            for (int r = 0; r < 4; ++r) l_run[r] += rsum[r];
        }
        __syncthreads();   // all waves done reading K_lds -> its head may hold P now

        if (active) {
            // ---- P: C-layout -> A-fragment layout via per-wave LDS transpose ----
            bf16* Pw = K_lds + wave*1024;   // 16x64 bf16 = 2KB per wave
#pragma unroll
            for (int n = 0; n < 4; ++n) {
                const int col = n*16 + l16;
#pragma unroll
                for (int r = 0; r < 4; ++r) {
                    const int row = 4*lhi + r;
                    Pw[row*64 + (col ^ ((row & 7) << 3))] = (bf16)p[n][r];
                }
            }
            asm volatile("s_waitcnt lgkmcnt(0)" ::: "memory");
            __builtin_amdgcn_sched_barrier(0);
            bf16x8 pa[2];
#pragma unroll
            for (int ksb = 0; ksb < 2; ++ksb) {
                const int row = l16;
                const int off = ksb*32 + 8*lhi;
                pa[ksb] = *(const bf16x8*)(Pw + row*64 + (off ^ ((row & 7) << 3)));
            }
            // ---- PV ----
            __builtin_amdgcn_s_setprio(1);
#pragma unroll
            for (int t = 0; t < 16; ++t) {
                const int d = t*16 + l16;
#pragma unroll
                for (int ksb = 0; ksb < 2; ++ksb) {
                    const int off = ksb*32 + 8*lhi;
                    bf16x8 vf = *(const bf16x8*)(V_lds + d*64 + (off ^ ((d & 7) << 3)));
                    oacc[t] = __builtin_amdgcn_mfma_f32_16x16x32_bf16(pa[ksb], vf, oacc[t], 0, 0, 0);
                }
            }
            __builtin_amdgcn_s_setprio(0);
        }
        __syncthreads();   // P/V reads complete before staging overwrites
        if (more)
            stage_write(K_lds, V_lds, tid, kr, vr);
        __syncthreads();   // next tile visible
    }

    // ---- write partials (merge kernel combines) ----
    const int ksOff = ks * NROWS;
#pragma unroll
    for (int r = 0; r < 4; ++r) {
        const int row = b*SEQ + q0w + 4*lhi + r;
        if (l16 == 0) { pm[ksOff + row] = m_run[r]; pl[ksOff + row] = l_run[r]; }
        float* dst = pO + (size_t)(ksOff + row)*DIM + l16;
#pragma unroll
        for (int t = 0; t < 16; ++t) dst[t*16] = oacc[t][r];
    }
}

// ================= merge two K-split partials -> att bf16 =================
__global__ __launch_bounds__(256) void merge_kernel(
    const float* __restrict__ pO, const float* __restrict__ pm,
    const float* __restrict__ pl, bf16* __restrict__ att)
{
    const int t = blockIdx.x*256 + threadIdx.x;
    const int row = t >> 5;
    const int d0 = (t & 31)*8;
    float m0 = pm[row],        m1 = pm[NROWS + row];
    float l0 = pl[row],        l1 = pl[NROWS + row];
    float M  = fmaxf(m0, m1);
    float e0 = __expf(m0 - M), e1 = __expf(m1 - M);
    float inv = 1.f / (l0*e0 + l1*e1);
    e0 *= inv; e1 *= inv;
    const float* p0 = pO + (size_t)row*DIM + d0;
    const float* p1 = pO + (size_t)NROWS*DIM + (size_t)row*DIM + d0;
    bf16x8 o;
#pragma unroll
    for (int j = 0; j < 8; ++j) o[j] = (bf16)(p0[j]*e0 + p1[j]*e1);
    *(bf16x8*)(att + (size_t)row*DIM + d0) = o;
}

// ================= launcher =================
extern "C" void kernel_launch(void* const* d_in, const int* in_sizes, int n_in,
                              void* d_out, int out_size, void* d_ws, size_t ws_size,
                              hipStream_t stream)
{
    (void)in_sizes; (void)n_in; (void)out_size; (void)ws_size;
    const float* queries = (const float*)d_in[0];
    const float* keys    = (const float*)d_in[1];
    const float* values  = (const float*)d_in[2];
    const int*   mask    = (const int*)  d_in[3];
    const float* Wq = (const float*)d_in[4];  const float* bq = (const float*)d_in[5];
    const float* Wk = (const float*)d_in[6];  const float* bk = (const float*)d_in[7];
    const float* Wv = (const float*)d_in[8];  const float* bv = (const float*)d_in[9];
    const float* Wo = (const float*)d_in[10]; const float* bo = (const float*)d_in[11];

    char* ws = (char*)d_ws;
    bf16* WqB = (bf16*)(ws);
    bf16* WkB = (bf16*)(ws + (size_t)(1<<17));
    bf16* WvB = (bf16*)(ws + (size_t)2*(1<<17));
    bf16* WoB = (bf16*)(ws + (size_t)3*(1<<17));
    bf16* Qp  = (bf16*)(ws + (size_t)(1<<20));
    bf16* Kp  = (bf16*)(ws + (size_t)(1<<20) + (size_t)(1<<23));
    bf16* Vt  = (bf16*)(ws + (size_t)(1<<20) + (size_t)2*(1<<23));
    bf16* att = (bf16*)(ws + (size_t)(1<<20) + (size_t)3*(1<<23));
    float* pm = (float*)(ws + (size_t)(1<<20) + (size_t)4*(1<<23));
    float* pl = pm + 2*NROWS;
    float* pO = (float*)(ws + (size_t)(1<<20) + (size_t)4*(1<<23) + (size_t)(1<<18));

    cvt_w_kernel<<<dim3(64,4), 256, 0, stream>>>(Wq, Wk, Wv, Wo, WqB, WkB, WvB, WoB);
    proj_kernel<0,false,true ><<<dim3(512), 256, 0, stream>>>(queries, WqB, bq, Qp);
    proj_kernel<0,false,false><<<dim3(512), 256, 0, stream>>>(keys,    WkB, bk, Kp);
    proj_kernel<1,false,false><<<dim3(512), 256, 0, stream>>>(values,  WvB, bv, Vt);
    attn_kernel<<<dim3(NBATCH,64,2), 256, 0, stream>>>(Qp, Kp, Vt, mask, pm, pl, pO);
    merge_kernel<<<dim3(NROWS/8), 256, 0, stream>>>(pO, pm, pl, att);
    proj_kernel<2,true,false><<<dim3(512), 256, 0, stream>>>(att, WoB, bo, d_out);
}